// Round 8
// baseline (75.209 us; speedup 1.0000x reference)
//
#include <hip/hip_runtime.h>

// GradientCurvatureAttention: fused depthwise-conv + curvature + channel-softmax + scale.
// x: [B=16, C=128, H=128, W=128] fp32, NCHW. out: same shape.
//
// Round 8: two output rows per thread. Rows (h, h+1) share the loads of the
// two middle input rows: 4 row-loads per channel-iter serve 8 output pixels
// (VMEM/px 0.75 -> 0.5 in pass 1). Top row is fully computed before the
// bottom row to keep the live register set flat. CGRP=16 x CPW=8, block
// (32,16)=512, grid 1024. No min-occupancy bound (forced bounds spill).

#define GCA_B 16
#define GCA_C 128
#define GCA_H 128
#define GCA_W 128
#define CGRP  16           // channel groups (blockDim.y)
#define CPW   (GCA_C/CGRP) // 8 channels per group

__device__ __forceinline__ float gca_score8(float cpl, float cpc, float cpr,
                                            float cml, float cmc, float cmr,
                                            float cyl, float cyc, float cyr) {
    const float Gx  = cpl - cpr;                       // [1,2,1]v x [1,0,-1]h
    const float Gy  = fmaf(2.f, cmc, cml + cmr);       // [1,0,-1]v x [1,2,1]h
    const float Ixx = fmaf(-2.f, cpc, cpl + cpr);      // [1,2,1]v x [1,-2,1]h
    const float Ixy = cmr - cml;                       // [1,0,-1]v x [-1,0,1]h
    const float Iyy = fmaf(2.f, cyc, cyl + cyr);       // [1,-2,1]v x [1,2,1]h
    const float gy2 = Gy * Gy;
    const float g2e = fmaf(Gx, Gx, gy2 + 1e-6f);
    const float r   = rsqrtf(g2e);
    const float gm  = g2e * r;                         // sqrt(g2e)
    const float t   = Gx * Iyy;
    const float p   = Gy * Ixy;
    const float inner = fmaf(-2.f, p, t);              // Gx*Iyy - 2*Gy*Ixy
    const float q   = gy2 * Ixx;
    const float num = fmaf(Gx, inner, q);
    const float r3  = (r * r) * r;
    return fmaf(num, r3, gm);                          // grad_mag + curvature
}

// Column sums (vertical [1,2,1] / [1,0,-1] / [1,-2,1]) for a 3-row window,
// 4 own columns + shuffled halo columns, then 4 scores + running max.
#define GCA_ROW_SCORES(vA, vB, vC, scv, lmaxv)                                 \
    {                                                                          \
        const float cpA = fmaf(2.f, (vB).x, (vA).x + (vC).x);                  \
        const float cmA = (vA).x - (vC).x;                                     \
        const float cyA = fmaf(-4.f, (vB).x, cpA);                             \
        const float cpB = fmaf(2.f, (vB).y, (vA).y + (vC).y);                  \
        const float cmB = (vA).y - (vC).y;                                     \
        const float cyB = fmaf(-4.f, (vB).y, cpB);                             \
        const float cpC = fmaf(2.f, (vB).z, (vA).z + (vC).z);                  \
        const float cmC = (vA).z - (vC).z;                                     \
        const float cyC = fmaf(-4.f, (vB).z, cpC);                             \
        const float cpD = fmaf(2.f, (vB).w, (vA).w + (vC).w);                  \
        const float cmD = (vA).w - (vC).w;                                     \
        const float cyD = fmaf(-4.f, (vB).w, cpD);                             \
        const float cpL = __shfl_up(cpD, 1) * mwA;                             \
        const float cmL = __shfl_up(cmD, 1) * mwA;                             \
        const float cyL = __shfl_up(cyD, 1) * mwA;                             \
        const float cpR = __shfl_down(cpA, 1) * mwB;                           \
        const float cmR = __shfl_down(cmA, 1) * mwB;                           \
        const float cyR = __shfl_down(cyA, 1) * mwB;                           \
        (scv).x = gca_score8(cpL, cpA, cpB, cmL, cmA, cmB, cyL, cyA, cyB);     \
        (scv).y = gca_score8(cpA, cpB, cpC, cmA, cmB, cmC, cyA, cyB, cyC);     \
        (scv).z = gca_score8(cpB, cpC, cpD, cmB, cmC, cmD, cyB, cyC, cyD);     \
        (scv).w = gca_score8(cpC, cpD, cpR, cmC, cmD, cmR, cyC, cyD, cyR);     \
        (lmaxv).x = fmaxf((lmaxv).x, (scv).x);                                 \
        (lmaxv).y = fmaxf((lmaxv).y, (scv).y);                                 \
        (lmaxv).z = fmaxf((lmaxv).z, (scv).z);                                 \
        (lmaxv).w = fmaxf((lmaxv).w, (scv).w);                                 \
    }

__global__ __launch_bounds__(512) void gca_fused8(const float* __restrict__ x,
                                                  float* __restrict__ out) {
    const int tx = threadIdx.x;                 // 0..31 : pixel quad, w0 = 4*tx
    const int ty = threadIdx.y;                 // 0..15 : channel group

    // XCD swizzle: 1024 blocks (= B*H/2, row-pair minor), 128 ids per XCD.
    const int id  = blockIdx.x;
    const int swz = ((id & 7) << 7) | (id >> 3);
    const int hq  = swz & 63;                   // row-pair index
    const int b   = swz >> 6;
    const int h0  = hq * 2;                     // top output row
    const int h1  = h0 + 1;                     // bottom output row

    const int w0 = tx * 4;
    const int c0 = ty * CPW;

    const int hmm = (h0 > 0) ? h0 - 1 : 0;          // row above top
    const int hpp = (h1 < GCA_H - 1) ? h1 + 1 : GCA_H - 1;  // row below bottom
    const float mTop = (h0 > 0) ? 1.f : 0.f;
    const float mBot = (h1 < GCA_H - 1) ? 1.f : 0.f;
    const float mwA = (tx > 0) ? 1.f : 0.f;    // left halo exists
    const float mwB = (tx < 31) ? 1.f : 0.f;   // right halo exists

    const size_t plane = (size_t)GCA_H * GCA_W;
    const float* base = x   + ((size_t)b * GCA_C + c0) * plane;
    float* obase      = out + ((size_t)b * GCA_C + c0) * plane;

    const int offm = hmm * GCA_W + w0;   // h0-1 (clamped)
    const int off0 = h0  * GCA_W + w0;   // h0
    const int off1 = h1  * GCA_W + w0;   // h1
    const int offp = hpp * GCA_W + w0;   // h1+1 (clamped)

    float4 sT[CPW], sB[CPW];             // scores, then exp values
    float4 lmaxT = make_float4(-3.0e38f, -3.0e38f, -3.0e38f, -3.0e38f);
    float4 lmaxB = lmaxT;

    // Pass 1: conv + curvature scores, 8 px (2 rows x 4 cols) x 8 channels.
    #pragma unroll
    for (int i = 0; i < CPW; ++i) {
        const float* p = base + (size_t)i * plane;
        float4 vm = *(const float4*)(p + offm);
        const float4 v0 = *(const float4*)(p + off0);
        const float4 v1 = *(const float4*)(p + off1);
        float4 vp = *(const float4*)(p + offp);
        vm.x *= mTop; vm.y *= mTop; vm.z *= mTop; vm.w *= mTop;
        vp.x *= mBot; vp.y *= mBot; vp.z *= mBot; vp.w *= mBot;

        GCA_ROW_SCORES(vm, v0, v1, sT[i], lmaxT);   // window (h0-1, h0, h1)
        GCA_ROW_SCORES(v0, v1, vp, sB[i], lmaxB);   // window (h0, h1, h1+1)
    }

    // Cross-group softmax reduction (per pixel, over the 16 channel groups).
    __shared__ float4 redmaxT[CGRP][32];
    __shared__ float4 redmaxB[CGRP][32];
    __shared__ float4 redsumT[CGRP][32];
    __shared__ float4 redsumB[CGRP][32];

    redmaxT[ty][tx] = lmaxT;
    redmaxB[ty][tx] = lmaxB;
    __syncthreads();
    float4 gmaxT = make_float4(-3.0e38f, -3.0e38f, -3.0e38f, -3.0e38f);
    float4 gmaxB = gmaxT;
    #pragma unroll
    for (int g = 0; g < CGRP; ++g) {
        const float4 mt = redmaxT[g][tx];
        const float4 mb = redmaxB[g][tx];
        gmaxT.x = fmaxf(gmaxT.x, mt.x); gmaxT.y = fmaxf(gmaxT.y, mt.y);
        gmaxT.z = fmaxf(gmaxT.z, mt.z); gmaxT.w = fmaxf(gmaxT.w, mt.w);
        gmaxB.x = fmaxf(gmaxB.x, mb.x); gmaxB.y = fmaxf(gmaxB.y, mb.y);
        gmaxB.z = fmaxf(gmaxB.z, mb.z); gmaxB.w = fmaxf(gmaxB.w, mb.w);
    }

    float4 lsumT = make_float4(0.f, 0.f, 0.f, 0.f);
    float4 lsumB = lsumT;
    #pragma unroll
    for (int i = 0; i < CPW; ++i) {
        float4 eT, eB;
        eT.x = __expf(sT[i].x - gmaxT.x); eT.y = __expf(sT[i].y - gmaxT.y);
        eT.z = __expf(sT[i].z - gmaxT.z); eT.w = __expf(sT[i].w - gmaxT.w);
        eB.x = __expf(sB[i].x - gmaxB.x); eB.y = __expf(sB[i].y - gmaxB.y);
        eB.z = __expf(sB[i].z - gmaxB.z); eB.w = __expf(sB[i].w - gmaxB.w);
        sT[i] = eT; sB[i] = eB;
        lsumT.x += eT.x; lsumT.y += eT.y; lsumT.z += eT.z; lsumT.w += eT.w;
        lsumB.x += eB.x; lsumB.y += eB.y; lsumB.z += eB.z; lsumB.w += eB.w;
    }
    redsumT[ty][tx] = lsumT;
    redsumB[ty][tx] = lsumB;
    __syncthreads();
    float4 totT = make_float4(0.f, 0.f, 0.f, 0.f);
    float4 totB = totT;
    #pragma unroll
    for (int g = 0; g < CGRP; ++g) {
        const float4 st = redsumT[g][tx];
        const float4 sb = redsumB[g][tx];
        totT.x += st.x; totT.y += st.y; totT.z += st.z; totT.w += st.w;
        totB.x += sb.x; totB.y += sb.y; totB.z += sb.z; totB.w += sb.w;
    }
    const float invTx = 1.f / totT.x, invTy = 1.f / totT.y;
    const float invTz = 1.f / totT.z, invTw = 1.f / totT.w;
    const float invBx = 1.f / totB.x, invBy = 1.f / totB.y;
    const float invBz = 1.f / totB.z, invBw = 1.f / totB.w;

    // Epilogue: out = (softmax + 1) * x; center rows reloaded (L2-resident).
    #pragma unroll
    for (int i = 0; i < CPW; ++i) {
        const float4 xT = *(const float4*)(base + (size_t)i * plane + off0);
        const float4 xB = *(const float4*)(base + (size_t)i * plane + off1);
        float4 oT, oB;
        oT.x = fmaf(sT[i].x * invTx, xT.x, xT.x);
        oT.y = fmaf(sT[i].y * invTy, xT.y, xT.y);
        oT.z = fmaf(sT[i].z * invTz, xT.z, xT.z);
        oT.w = fmaf(sT[i].w * invTw, xT.w, xT.w);
        oB.x = fmaf(sB[i].x * invBx, xB.x, xB.x);
        oB.y = fmaf(sB[i].y * invBy, xB.y, xB.y);
        oB.z = fmaf(sB[i].z * invBz, xB.z, xB.z);
        oB.w = fmaf(sB[i].w * invBw, xB.w, xB.w);
        *(float4*)(obase + (size_t)i * plane + off0) = oT;
        *(float4*)(obase + (size_t)i * plane + off1) = oB;
    }
}

extern "C" void kernel_launch(void* const* d_in, const int* in_sizes, int n_in,
                              void* d_out, int out_size, void* d_ws, size_t ws_size,
                              hipStream_t stream) {
    (void)in_sizes; (void)n_in; (void)d_ws; (void)ws_size; (void)out_size;
    const float* x = (const float*)d_in[0];
    float* out = (float*)d_out;
    dim3 block(32, CGRP, 1);
    dim3 grid(GCA_B * GCA_H / 2, 1, 1);   // 1024 blocks, swizzled in-kernel
    gca_fused8<<<grid, block, 0, stream>>>(x, out);
}